// Round 6
// baseline (70.803 us; speedup 1.0000x reference)
//
#include <hip/hip_runtime.h>

// B=256, T=256, D=384, HD=64
typedef __attribute__((ext_vector_type(8))) short bf16x8;
typedef __attribute__((ext_vector_type(4))) float f32x4;

__device__ inline unsigned short f2bf(float f) {
    unsigned u = __float_as_uint(f);
    return (unsigned short)((u + 0x7fffu + ((u >> 16) & 1u)) >> 16);
}
__device__ inline bf16x8 pack8(float4 a, float4 b) {
    bf16x8 t;
    t[0] = (short)f2bf(a.x); t[1] = (short)f2bf(a.y);
    t[2] = (short)f2bf(a.z); t[3] = (short)f2bf(a.w);
    t[4] = (short)f2bf(b.x); t[5] = (short)f2bf(b.y);
    t[6] = (short)f2bf(b.z); t[7] = (short)f2bf(b.w);
    return t;
}

// ---------------------------------------------------------------------------
// Kernel 0: concatenate + convert W = [Wq;Wk;Wv] (192x384 f32) -> bf16
// ---------------------------------------------------------------------------
__global__ void wconv(const float* __restrict__ Wq, const float* __restrict__ Wk,
                      const float* __restrict__ Wv, short* __restrict__ Wcat) {
    int i = blockIdx.x * 256 + threadIdx.x;
    if (i >= 192 * 384) return;
    int row = i / 384;
    int col = i - row * 384;
    const float* src = row < 64 ? (Wq + row * 384)
                     : row < 128 ? (Wk + (row - 64) * 384)
                                 : (Wv + (row - 128) * 384);
    Wcat[i] = (short)f2bf(src[col]);
}

// ---------------------------------------------------------------------------
// Fused kernel: block = 1 batch (grid 256 = 1 block/CU), 8 waves (512 thr).
// Phase 1 (proj): R1-R5 were DRAM-row-activate-bound: x was read in 128B
//   strips at stride 1536B (k-chunked) -> ~1.1 TB/s effective HBM. Fix:
//   x rows are wave-private (wave owns its 64 M-rows), so load x DIRECTLY
//   into register A-frags in full-row order: per 16-row group, 12
//   consecutive dwordx4 sweep 768B contiguous per row (per K-half).
//   K split in 2 halves of 192 (xr[4][6] = 96 VGPR per half).
//   W k-window staged in LDS (L2-hot, coalesced, double-buffered, one
//   cheap barrier/step). A/B frags keep the identical k-gather
//   (permutation-immune); C/D layout verified.
// Phase 2 (attn): R2-R5-verified causal online-softmax MFMA attention.
//   Q,K row-major stride 72; V transposed [64][264] XOR-swizzled.
// ---------------------------------------------------------------------------
#define PROJ_STEP(S2, S)                                                      \
    {                                                                         \
        uint2 w0n, w1n, w2n;                                                  \
        if ((S) < 11) {                                                       \
            w0n = *(const uint2*)(gw + ((S) + 1) * 32);                       \
            w1n = *(const uint2*)(gw + ((S) + 1) * 32 + 24576);               \
            w2n = *(const uint2*)(gw + ((S) + 1) * 32 + 49152);               \
        }                                                                     \
        const short* wb = Wst + ((S) & 1) * (192 * 40);                       \
        bf16x8 bfr[6];                                                        \
        _Pragma("unroll")                                                     \
        for (int nj = 0; nj < 6; ++nj)                                        \
            bfr[nj] = *(const bf16x8*)&wb[(wn + 16 * nj + c) * 40 + g * 8];   \
        _Pragma("unroll")                                                     \
        for (int mi = 0; mi < 4; ++mi)                                        \
            _Pragma("unroll")                                                 \
            for (int nj = 0; nj < 6; ++nj)                                    \
                acc[mi][nj] = __builtin_amdgcn_mfma_f32_16x16x32_bf16(        \
                    xr[mi][(S2)], bfr[nj], acc[mi][nj], 0, 0, 0);             \
        if ((S) < 11) {                                                       \
            short* wd = Wst + (((S) + 1) & 1) * (192 * 40);                   \
            *(uint2*)&wd[(srow)       * 40 + sc4 * 4] = w0n;                  \
            *(uint2*)&wd[(srow +  64) * 40 + sc4 * 4] = w1n;                  \
            *(uint2*)&wd[(srow + 128) * 40 + sc4 * 4] = w2n;                  \
        }                                                                     \
        __syncthreads();                                                      \
    }

#define LOAD_XHALF(HB)                                                        \
    {                                                                         \
        _Pragma("unroll")                                                     \
        for (int mp = 0; mp < 2; ++mp) {                                      \
            float4 ta[12], tb[12];                                            \
            const float* ra = xbase + (2 * mp)     * 16 * 384 + (HB) * 192;   \
            const float* rb = xbase + (2 * mp + 1) * 16 * 384 + (HB) * 192;   \
            _Pragma("unroll")                                                 \
            for (int s2 = 0; s2 < 6; ++s2) {                                  \
                ta[2 * s2]     = *(const float4*)(ra + s2 * 32);              \
                ta[2 * s2 + 1] = *(const float4*)(ra + s2 * 32 + 4);          \
            }                                                                 \
            _Pragma("unroll")                                                 \
            for (int s2 = 0; s2 < 6; ++s2) {                                  \
                tb[2 * s2]     = *(const float4*)(rb + s2 * 32);              \
                tb[2 * s2 + 1] = *(const float4*)(rb + s2 * 32 + 4);          \
            }                                                                 \
            _Pragma("unroll")                                                 \
            for (int s2 = 0; s2 < 6; ++s2)                                    \
                xr[2 * mp][s2] = pack8(ta[2 * s2], ta[2 * s2 + 1]);           \
            _Pragma("unroll")                                                 \
            for (int s2 = 0; s2 < 6; ++s2)                                    \
                xr[2 * mp + 1][s2] = pack8(tb[2 * s2], tb[2 * s2 + 1]);       \
        }                                                                     \
    }

__global__ __launch_bounds__(512, 2) void fused_attn(
    const float* __restrict__ x, const short* __restrict__ Wcat,
    float* __restrict__ out) {
    __shared__ short QK[2 * 256 * 72];     // Q,K final (phase 2)
    __shared__ short Vt[64 * 264];
    __shared__ short Wst[2 * 192 * 40];    // W k-window, double-buffered
    __shared__ short Pb[8][16 * 40];
    short* const Qlds = QK;
    short* const Ksh  = QK + 256 * 72;

    const int tid = threadIdx.x;
    const int wv = tid >> 6, lane = tid & 63;
    const int g = lane >> 4, c = lane & 15;
    const int wm = (wv >> 1) * 64, wn = (wv & 1) * 96;
    const int b = blockIdx.x;

    // ---------------- Phase 1: QKV projection ----------------
    const int srow = tid >> 3;             // W staging: rows srow+64*r
    const int sc4  = tid & 7;
    const short* gw = Wcat + srow * 384 + sc4 * 4;

    f32x4 acc[4][6];
#pragma unroll
    for (int i = 0; i < 4; ++i)
#pragma unroll
        for (int j = 0; j < 6; ++j) acc[i][j] = (f32x4){0.f, 0.f, 0.f, 0.f};

    // stage W step 0 (coalesced, L2-hot)
    {
        uint2 w0 = *(const uint2*)(gw);
        uint2 w1 = *(const uint2*)(gw + 24576);
        uint2 w2 = *(const uint2*)(gw + 49152);
        *(uint2*)&Wst[(srow)       * 40 + sc4 * 4] = w0;
        *(uint2*)&Wst[(srow +  64) * 40 + sc4 * 4] = w1;
        *(uint2*)&Wst[(srow + 128) * 40 + sc4 * 4] = w2;
    }

    // x: full-row streaming into register frags.  Lane (g,c) of wave wm:
    // rows wm+16*mi+c, cols hb*192 + s2*32 + g*8 (8 f32 -> 1 bf16x8)
    const float* xbase = x + ((size_t)b * 256 + wm + c) * 384 + g * 8;
    bf16x8 xr[4][6];

    LOAD_XHALF(0)
    __syncthreads();                       // W0 staged

    PROJ_STEP(0, 0) PROJ_STEP(1, 1) PROJ_STEP(2, 2)
    PROJ_STEP(3, 3) PROJ_STEP(4, 4) PROJ_STEP(5, 5)

    LOAD_XHALF(1)                          // regs private: no barrier needed

    PROJ_STEP(0, 6) PROJ_STEP(1, 7) PROJ_STEP(2, 8)
    PROJ_STEP(3, 9) PROJ_STEP(4, 10) PROJ_STEP(5, 11)

    // epilogue: acc -> LDS.  C/D layout: col = c, row = 4g + r (verified).
#pragma unroll
    for (int mi = 0; mi < 4; ++mi) {
#pragma unroll
        for (int nj = 0; nj < 6; ++nj) {
            const int colb = wn + 16 * nj;          // wave-uniform
            const int row = wm + 16 * mi + 4 * g;
            if (colb < 64) {
#pragma unroll
                for (int r = 0; r < 4; ++r)
                    Qlds[(row + r) * 72 + colb + c] = (short)f2bf(acc[mi][nj][r]);
            } else if (colb < 128) {
#pragma unroll
                for (int r = 0; r < 4; ++r)
                    Ksh[(row + r) * 72 + (colb - 64) + c] = (short)f2bf(acc[mi][nj][r]);
            } else {
                const int h = colb - 128 + c;
                const int swz = ((h >> 3) & 7) << 3;
#pragma unroll
                for (int r = 0; r < 4; ++r)
                    Vt[(h * 264 + row + r) ^ swz] = (short)f2bf(acc[mi][nj][r]);
            }
        }
    }
    __syncthreads();

    // ---------------- Phase 2: causal attention ----------------
    for (int half = 0; half < 2; ++half) {
        const int q0 = (half == 0) ? 16 * wv : 240 - 16 * wv;
        bf16x8 qf0 = *(const bf16x8*)&Qlds[(q0 + c) * 72 + g * 8];
        bf16x8 qf1 = *(const bf16x8*)&Qlds[(q0 + c) * 72 + 32 + g * 8];
        f32x4 o[4];
#pragma unroll
        for (int nj = 0; nj < 4; ++nj) o[nj] = (f32x4){0.f, 0.f, 0.f, 0.f};
        float m[4] = {-INFINITY, -INFINITY, -INFINITY, -INFINITY};
        float ls[4] = {0.f, 0.f, 0.f, 0.f};
        const int jmax = (q0 + 15) >> 5;

        for (int j = 0; j <= jmax; ++j) {
            f32x4 s0 = {0.f, 0.f, 0.f, 0.f}, s1 = {0.f, 0.f, 0.f, 0.f};
            {
                bf16x8 kf;
                kf = *(const bf16x8*)&Ksh[(32 * j + c) * 72 + g * 8];
                s0 = __builtin_amdgcn_mfma_f32_16x16x32_bf16(qf0, kf, s0, 0, 0, 0);
                kf = *(const bf16x8*)&Ksh[(32 * j + c) * 72 + 32 + g * 8];
                s0 = __builtin_amdgcn_mfma_f32_16x16x32_bf16(qf1, kf, s0, 0, 0, 0);
                kf = *(const bf16x8*)&Ksh[(32 * j + 16 + c) * 72 + g * 8];
                s1 = __builtin_amdgcn_mfma_f32_16x16x32_bf16(qf0, kf, s1, 0, 0, 0);
                kf = *(const bf16x8*)&Ksh[(32 * j + 16 + c) * 72 + 32 + g * 8];
                s1 = __builtin_amdgcn_mfma_f32_16x16x32_bf16(qf1, kf, s1, 0, 0, 0);
            }
            float t0[4], t1[4];
#pragma unroll
            for (int r = 0; r < 4; ++r) {
                t0[r] = s0[r] * 0.125f;
                t1[r] = s1[r] * 0.125f;
            }
            if (j == jmax) {   // wave-uniform: diagonal tile, causal mask
                int q = q0 + 4 * g;
#pragma unroll
                for (int r = 0; r < 4; ++r) {
                    if (32 * j + c > q + r) t0[r] = -INFINITY;
                    if (32 * j + 16 + c > q + r) t1[r] = -INFINITY;
                }
            }
            float corr[4], p0[4], p1[4];
#pragma unroll
            for (int r = 0; r < 4; ++r) {
                float v = fmaxf(t0[r], t1[r]);
#pragma unroll
                for (int off = 1; off < 16; off <<= 1) v = fmaxf(v, __shfl_xor(v, off, 16));
                float mn = fmaxf(m[r], v);
                corr[r] = __expf(m[r] - mn);   // first tile: exp(-inf)=0
                m[r] = mn;
                p0[r] = __expf(t0[r] - mn);
                p1[r] = __expf(t1[r] - mn);
                float rs = p0[r] + p1[r];
#pragma unroll
                for (int off = 1; off < 16; off <<= 1) rs += __shfl_xor(rs, off, 16);
                ls[r] = ls[r] * corr[r] + rs;
            }
#pragma unroll
            for (int nj = 0; nj < 4; ++nj) {
                f32x4 t = o[nj];
                t[0] *= corr[0]; t[1] *= corr[1]; t[2] *= corr[2]; t[3] *= corr[3];
                o[nj] = t;
            }
            // P -> LDS (C/D rows) -> A-frag read (same-wave RAW, in-order LDS)
            short* pb = Pb[wv];
#pragma unroll
            for (int r = 0; r < 4; ++r) {
                pb[(4 * g + r) * 40 + c]      = (short)f2bf(p0[r]);
                pb[(4 * g + r) * 40 + 16 + c] = (short)f2bf(p1[r]);
            }
            bf16x8 pfa = *(const bf16x8*)&pb[c * 40 + g * 8];
#pragma unroll
            for (int nj = 0; nj < 4; ++nj) {
                int h = 16 * nj + c;
                int swz = ((2 * nj + (c >> 3)) & 7) << 3;
                bf16x8 vf = *(const bf16x8*)&Vt[(h * 264 + 32 * j + g * 8) ^ swz];
                o[nj] = __builtin_amdgcn_mfma_f32_16x16x32_bf16(pfa, vf, o[nj], 0, 0, 0);
            }
        }
        float inv[4];
#pragma unroll
        for (int r = 0; r < 4; ++r) inv[r] = 1.f / ls[r];
        float* ob = out + ((size_t)b * 256 + q0) * 64;
#pragma unroll
        for (int nj = 0; nj < 4; ++nj)
#pragma unroll
            for (int r = 0; r < 4; ++r)
                ob[(4 * g + r) * 64 + 16 * nj + c] = o[nj][r] * inv[r];
    }
}

// ---------------------------------------------------------------------------
extern "C" void kernel_launch(void* const* d_in, const int* in_sizes, int n_in,
                              void* d_out, int out_size, void* d_ws, size_t ws_size,
                              hipStream_t stream) {
    const float* x  = (const float*)d_in[0];
    const float* Wq = (const float*)d_in[1];
    const float* Wk = (const float*)d_in[2];
    const float* Wv = (const float*)d_in[3];
    float* out = (float*)d_out;

    short* Wcat = (short*)d_ws;   // 192*384 bf16 = 147 KB

    wconv<<<dim3(288), dim3(256), 0, stream>>>(Wq, Wk, Wv, Wcat);
    fused_attn<<<dim3(256), dim3(512), 0, stream>>>(x, Wcat, out);
}

// Round 7
// 47.025 us; speedup vs baseline: 1.5056x; 1.5056x over previous
//
#include <hip/hip_runtime.h>

// B=256, T=256, D=384, HD=64
typedef __attribute__((ext_vector_type(8))) short bf16x8;
typedef __attribute__((ext_vector_type(4))) float f32x4;

__device__ inline unsigned short f2bf(float f) {
    unsigned u = __float_as_uint(f);
    return (unsigned short)((u + 0x7fffu + ((u >> 16) & 1u)) >> 16);
}

__device__ inline void gload16(const void* g, void* l) {
    __builtin_amdgcn_global_load_lds(
        (const __attribute__((address_space(1))) unsigned*)g,
        (__attribute__((address_space(3))) unsigned*)l, 16, 0, 0);
}

// ---------------------------------------------------------------------------
// Kernel 0: W = [Wq;Wk;Wv] -> bf16, packed FRAG-MAJOR + PRE-SWIZZLED so the
// proj kernel can stage each BK=32 k-step as a pure linear 12 KB copy via
// global_load_lds and read B-frags as single b128s:
//   Wp[kc*6144 + (((g*192 + col) ^ g) << 3) + kl] = W[col][kc*32 + g*8 + kl]
// (g = k-subgroup 0..3; XOR ^g spreads the 16B chunks across banks; reader
//  applies the same XOR -> involution, rule #21.)
// ---------------------------------------------------------------------------
__global__ void wconv(const float* __restrict__ Wq, const float* __restrict__ Wk,
                      const float* __restrict__ Wv, short* __restrict__ Wp) {
    int i = blockIdx.x * 256 + threadIdx.x;
    if (i >= 192 * 384) return;
    int col = i / 384;          // output column 0..191 (h)
    int k   = i - col * 384;    // 0..383
    const float* src = col < 64 ? (Wq + col * 384)
                     : col < 128 ? (Wk + (col - 64) * 384)
                                 : (Wv + (col - 128) * 384);
    int kc = k >> 5, g = (k >> 3) & 3, kl = k & 7;
    Wp[kc * 6144 + (((g * 192 + col) ^ g) << 3) + kl] = (short)f2bf(src[k]);
}

// ---------------------------------------------------------------------------
// Kernel 1: QKV projection. 512 blocks x 256 thr (4 waves, 2Mx2N, wave=64x96),
// tile 128x192, BK=32, 12 steps. Staging via global_load_lds (width 16),
// double-buffered, issued BEFORE compute, vmcnt(0)+barrier per step (T3-min).
//   x: LDS linear [128][32] f32; SOURCE pre-swizzle: LDS 4-word chunk q of
//      row r holds global chunk q ^ (r&7); frag-read XORs back. Staging
//      instr = 8 rows x 128 B contiguous global (coalescing unchanged).
//   W: linear 12 KB copy of Wp (pre-swizzled by wconv).
// f32->bf16 conversion happens at frag-read (VALU idle anyway).
// Epilogue: repack through LDS, coalesced uint4 stores of Q/K/V bf16.
// ---------------------------------------------------------------------------
__global__ __launch_bounds__(256, 2) void qkv_proj(
    const float* __restrict__ x, const short* __restrict__ Wp,
    short* __restrict__ Qw, short* __restrict__ Kw, short* __restrict__ Vw) {
    __shared__ unsigned char LDSRAW[57344];   // x: 2x16KB | W: 2x12KB
    float* const xb0 = (float*)LDSRAW;
    float* const xb1 = xb0 + 4096;
    short* const wb0 = (short*)(LDSRAW + 32768);
    short* const wb1 = wb0 + 6144;

    const int tid = threadIdx.x;
    const int wv = tid >> 6, lane = tid & 63;
    const int g = lane >> 4, c = lane & 15;
    const int wm = (wv >> 1) * 64, wn = (wv & 1) * 96;
    const size_t m0 = (size_t)blockIdx.x * 128;

    f32x4 acc[4][6];
#pragma unroll
    for (int i = 0; i < 4; ++i)
#pragma unroll
        for (int j = 0; j < 6; ++j) acc[i][j] = (f32x4){0.f, 0.f, 0.f, 0.f};

    // per-lane source-swizzle constants for x staging
    const int xrow8 = lane >> 3;                       // 0..7
    const int xgcol = ((lane & 7) ^ xrow8) << 2;       // swizzled f32 col chunk

#define STAGE_X(KC, XB)                                                       \
    {                                                                         \
        _Pragma("unroll")                                                     \
        for (int i_ = 0; i_ < 4; ++i_) {                                      \
            int seg = wv * 4 + i_;                                            \
            const float* gp = x + (m0 + seg * 8 + xrow8) * 384 + (KC) * 32 + xgcol; \
            gload16(gp, (XB) + seg * 256);                                    \
        }                                                                     \
    }
#define STAGE_W(KC, WB)                                                       \
    {                                                                         \
        _Pragma("unroll")                                                     \
        for (int i_ = 0; i_ < 3; ++i_) {                                      \
            int seg = wv * 3 + i_;                                            \
            const short* gp = Wp + (KC) * 6144 + seg * 512 + lane * 8;        \
            gload16(gp, (WB) + seg * 512);                                    \
        }                                                                     \
    }

    STAGE_X(0, xb0)
    STAGE_W(0, wb0)
    asm volatile("s_waitcnt vmcnt(0)" ::: "memory");
    __syncthreads();

    for (int s = 0; s < 12; ++s) {
        if (s < 11) {                       // issue next-step staging EARLY
            if (s & 1) { STAGE_X(s + 1, xb0) STAGE_W(s + 1, wb0) }
            else       { STAGE_X(s + 1, xb1) STAGE_W(s + 1, wb1) }
        }
        const float* xb = (s & 1) ? xb1 : xb0;
        const short* wb = (s & 1) ? wb1 : wb0;
        bf16x8 af[4], bfr[6];
#pragma unroll
        for (int mi = 0; mi < 4; ++mi) {
            const int row = wm + 16 * mi + c;
            const int rx = row & 7;
            f32x4 lo = *(const f32x4*)&xb[row * 32 + (((2 * g) ^ rx) << 2)];
            f32x4 hi = *(const f32x4*)&xb[row * 32 + (((2 * g + 1) ^ rx) << 2)];
            bf16x8 t;
            t[0] = (short)f2bf(lo[0]); t[1] = (short)f2bf(lo[1]);
            t[2] = (short)f2bf(lo[2]); t[3] = (short)f2bf(lo[3]);
            t[4] = (short)f2bf(hi[0]); t[5] = (short)f2bf(hi[1]);
            t[6] = (short)f2bf(hi[2]); t[7] = (short)f2bf(hi[3]);
            af[mi] = t;
        }
#pragma unroll
        for (int nj = 0; nj < 6; ++nj)
            bfr[nj] = *(const bf16x8*)&wb[((g * 192 + wn + 16 * nj + c) ^ g) << 3];
#pragma unroll
        for (int mi = 0; mi < 4; ++mi)
#pragma unroll
            for (int nj = 0; nj < 6; ++nj)
                acc[mi][nj] = __builtin_amdgcn_mfma_f32_16x16x32_bf16(
                    af[mi], bfr[nj], acc[mi][nj], 0, 0, 0);
        asm volatile("s_waitcnt vmcnt(0)" ::: "memory");
        __syncthreads();
    }

    // epilogue: acc -> LDS repack -> coalesced bf16 stores.
    // C/D layout (verified): col = c, row = 4g + r within each 16x16 tile.
    short* ep = (short*)LDSRAW;             // 128x192 shorts = 48 KB
#pragma unroll
    for (int mi = 0; mi < 4; ++mi)
#pragma unroll
        for (int nj = 0; nj < 6; ++nj) {
            const int row = wm + 16 * mi + 4 * g;
#pragma unroll
            for (int r = 0; r < 4; ++r)
                ep[(row + r) * 192 + wn + 16 * nj + c] = (short)f2bf(acc[mi][nj][r]);
        }
    __syncthreads();
#pragma unroll
    for (int p = 0; p < 4; ++p) {
        int u = tid + 256 * p;              // 0..1023: row = u>>3, col8 = u&7
        int row = u >> 3, c8 = u & 7;
        *(uint4*)(Qw + (m0 + row) * 64 + c8 * 8) = *(const uint4*)&ep[row * 192 + c8 * 8];
        *(uint4*)(Kw + (m0 + row) * 64 + c8 * 8) = *(const uint4*)&ep[row * 192 + 64 + c8 * 8];
        *(uint4*)(Vw + (m0 + row) * 64 + c8 * 8) = *(const uint4*)&ep[row * 192 + 128 + c8 * 8];
    }
#undef STAGE_X
#undef STAGE_W
}

// ---------------------------------------------------------------------------
// Kernel 2: causal attention (R2/R5-verified logic). 256 blocks x 512 thr,
// LDS 79 KB -> 2 blocks/CU. K [256][72]; V transposed [64][264] XOR-swizzled;
// Q direct global->regs. Wave w: q-tiles 16w and 240-16w (9 kv-tiles each).
// ---------------------------------------------------------------------------
__global__ __launch_bounds__(512, 2) void attn_mfma(
    const short* __restrict__ Qw, const short* __restrict__ Kw,
    const short* __restrict__ Vw, float* __restrict__ out) {
    __shared__ short Ksh[256 * 72];
    __shared__ short Vt[64 * 264];
    __shared__ short Pb[8][640];
    const int tid = threadIdx.x;
    const int wv = tid >> 6, lane = tid & 63;
    const int g = lane >> 4, c = lane & 15;
    const int b = blockIdx.x;
    const short* Qg = Qw + b * 16384;
    const short* Kg = Kw + b * 16384;
    const short* Vg = Vw + b * 16384;

#pragma unroll
    for (int p = 0; p < 4; ++p) {
        int idx = tid + 512 * p;
        int r = idx >> 3, q8 = idx & 7;
        *(uint4*)&Ksh[r * 72 + q8 * 8] = *(const uint4*)(Kg + r * 64 + q8 * 8);
    }
#pragma unroll
    for (int p = 0; p < 4; ++p) {
        int idx = tid + 512 * p;
        int r = idx >> 3, q8 = idx & 7;
        uint4 v = *(const uint4*)(Vg + r * 64 + q8 * 8);
        unsigned vw[4] = {v.x, v.y, v.z, v.w};
        int swz = (q8 & 7) << 3;
#pragma unroll
        for (int w2 = 0; w2 < 4; ++w2) {
            int h0 = q8 * 8 + w2 * 2;
            Vt[((h0 + 0) * 264 + r) ^ swz] = (short)(vw[w2] & 0xffff);
            Vt[((h0 + 1) * 264 + r) ^ swz] = (short)(vw[w2] >> 16);
        }
    }
    __syncthreads();

    for (int half = 0; half < 2; ++half) {
        const int q0 = (half == 0) ? 16 * wv : 240 - 16 * wv;
        bf16x8 qf0 = *(const bf16x8*)(Qg + (q0 + c) * 64 + g * 8);
        bf16x8 qf1 = *(const bf16x8*)(Qg + (q0 + c) * 64 + 32 + g * 8);
        f32x4 o[4];
#pragma unroll
        for (int nj = 0; nj < 4; ++nj) o[nj] = (f32x4){0.f, 0.f, 0.f, 0.f};
        float m[4] = {-INFINITY, -INFINITY, -INFINITY, -INFINITY};
        float ls[4] = {0.f, 0.f, 0.f, 0.f};
        const int jmax = (q0 + 15) >> 5;

        for (int j = 0; j <= jmax; ++j) {
            f32x4 s0 = {0.f, 0.f, 0.f, 0.f}, s1 = {0.f, 0.f, 0.f, 0.f};
            {
                bf16x8 kf;
                kf = *(const bf16x8*)&Ksh[(32 * j + c) * 72 + g * 8];
                s0 = __builtin_amdgcn_mfma_f32_16x16x32_bf16(qf0, kf, s0, 0, 0, 0);
                kf = *(const bf16x8*)&Ksh[(32 * j + c) * 72 + 32 + g * 8];
                s0 = __builtin_amdgcn_mfma_f32_16x16x32_bf16(qf1, kf, s0, 0, 0, 0);
                kf = *(const bf16x8*)&Ksh[(32 * j + 16 + c) * 72 + g * 8];
                s1 = __builtin_amdgcn_mfma_f32_16x16x32_bf16(qf0, kf, s1, 0, 0, 0);
                kf = *(const bf16x8*)&Ksh[(32 * j + 16 + c) * 72 + 32 + g * 8];
                s1 = __builtin_amdgcn_mfma_f32_16x16x32_bf16(qf1, kf, s1, 0, 0, 0);
            }
            float t0[4], t1[4];
#pragma unroll
            for (int r = 0; r < 4; ++r) {
                t0[r] = s0[r] * 0.125f;
                t1[r] = s1[r] * 0.125f;
            }
            if (j == jmax) {   // wave-uniform: diagonal tile, causal mask
                int q = q0 + 4 * g;
#pragma unroll
                for (int r = 0; r < 4; ++r) {
                    if (32 * j + c > q + r) t0[r] = -INFINITY;
                    if (32 * j + 16 + c > q + r) t1[r] = -INFINITY;
                }
            }
            float corr[4], p0[4], p1[4];
#pragma unroll
            for (int r = 0; r < 4; ++r) {
                float v = fmaxf(t0[r], t1[r]);
#pragma unroll
                for (int off = 1; off < 16; off <<= 1) v = fmaxf(v, __shfl_xor(v, off, 16));
                float mn = fmaxf(m[r], v);
                corr[r] = __expf(m[r] - mn);   // first tile: exp(-inf)=0
                m[r] = mn;
                p0[r] = __expf(t0[r] - mn);
                p1[r] = __expf(t1[r] - mn);
                float rs = p0[r] + p1[r];
#pragma unroll
                for (int off = 1; off < 16; off <<= 1) rs += __shfl_xor(rs, off, 16);
                ls[r] = ls[r] * corr[r] + rs;
            }
#pragma unroll
            for (int nj = 0; nj < 4; ++nj) {
                f32x4 t = o[nj];
                t[0] *= corr[0]; t[1] *= corr[1]; t[2] *= corr[2]; t[3] *= corr[3];
                o[nj] = t;
            }
            short* pb = Pb[wv];
#pragma unroll
            for (int r = 0; r < 4; ++r) {
                pb[(4 * g + r) * 40 + c]      = (short)f2bf(p0[r]);
                pb[(4 * g + r) * 40 + 16 + c] = (short)f2bf(p1[r]);
            }
            bf16x8 pfa = *(const bf16x8*)&pb[c * 40 + g * 8];
#pragma unroll
            for (int nj = 0; nj < 4; ++nj) {
                int h = 16 * nj + c;
                int swz = ((2 * nj + (c >> 3)) & 7) << 3;
                bf16x8 vf = *(const bf16x8*)&Vt[(h * 264 + 32 * j + g * 8) ^ swz];
                o[nj] = __builtin_amdgcn_mfma_f32_16x16x32_bf16(pfa, vf, o[nj], 0, 0, 0);
            }
        }
        float inv[4];
#pragma unroll
        for (int r = 0; r < 4; ++r) inv[r] = 1.f / ls[r];
        float* ob = out + ((size_t)b * 256 + q0) * 64;
#pragma unroll
        for (int nj = 0; nj < 4; ++nj)
#pragma unroll
            for (int r = 0; r < 4; ++r)
                ob[(4 * g + r) * 64 + 16 * nj + c] = o[nj][r] * inv[r];
    }
}

// ---------------------------------------------------------------------------
extern "C" void kernel_launch(void* const* d_in, const int* in_sizes, int n_in,
                              void* d_out, int out_size, void* d_ws, size_t ws_size,
                              hipStream_t stream) {
    const float* x  = (const float*)d_in[0];
    const float* Wq = (const float*)d_in[1];
    const float* Wk = (const float*)d_in[2];
    const float* Wv = (const float*)d_in[3];
    float* out = (float*)d_out;

    // ws: Q | K | V (each 65536*64 bf16 = 8 MB) | Wp (73728 shorts)
    short* Qws = (short*)d_ws;
    short* Kws = Qws + (size_t)65536 * 64;
    short* Vws = Kws + (size_t)65536 * 64;
    short* Wp  = Vws + (size_t)65536 * 64;

    wconv<<<dim3(288), dim3(256), 0, stream>>>(Wq, Wk, Wv, Wp);
    qkv_proj<<<dim3(512), dim3(256), 0, stream>>>(x, Wp, Qws, Kws, Vws);
    attn_mfma<<<dim3(256), dim3(512), 0, stream>>>(Qws, Kws, Vws, out);
}